// Round 7
// baseline (114.689 us; speedup 1.0000x reference)
//
#include <hip/hip_runtime.h>
#include <math.h>

#define B 32
#define T 262144
#define NFR 250
#define NCH 64              // chunks per row
#define CHUNK 4096          // elements per chunk
#define NTHR 256
#define EPT 16              // elements per thread
#define NBLK (B * NCH)      // 2048 blocks

// d_ws layout: [flags int[2048] | counter int | pad | vals double[2048]]
#define WS_VALS_OFF 8448    // bytes; memset clears [0, WS_VALS_OFF)

// [256][16] f32 tile swizzle: XOR on e bits [3:2] keeps float4 alignment and
// makes per-owner b128 and linear coalesced b128 both bank-conflict-free.
__device__ __forceinline__ int swz16(int t, int e) {
  return t * 16 + (e ^ ((t & 3) << 2));
}

// Per-op envelope line params at local frame i0s: env*mi = c0 + s0*pr + dd*max(pr-1,0)
__device__ __forceinline__ void env_params(const float* __restrict__ adsr,
                                           int row, int k, int i0s, float em,
                                           float& c0, float& s0, float& dd) {
  const float* ap = adsr + row * 11 + k;
  float fl = ap[0], pk = ap[1];
  float a = fmaxf(ap[2], 1e-5f);
  float de = fmaxf(ap[3], 1e-5f);
  float ss = ap[4];
  float r = fmaxf(ap[5], 1e-5f);
  float ra = 1.0f / a, rd = 1.0f / de, rr = 1.0f / r;
  float e3[3];
#pragma unroll
  for (int j = 0; j < 3; ++j) {
    int fi = i0s + j;
    fi = (fi < NFR - 1) ? fi : NFR - 1;
    float tt = (float)fi * (1.0f / 249.0f);
    float att = fminf(fmaxf(tt * ra, 0.0f), 1.0f);
    float dec = fminf(fmaxf((tt - a) * rd, 0.0f), 1.0f);
    float rel = fminf(fmaxf((tt - (1.0f - r)) * rr, 0.0f), 1.0f);
    float env = att * (1.0f - (1.0f - ss) * dec) * (1.0f - rel);
    e3[j] = fl + (pk - fl) * env;
  }
  c0 = e3[0] * em;
  s0 = (e3[1] - e3[0]) * em;
  dd = (e3[2] - e3[1]) * em - s0;
}

// ============ single-pass ticketed chained-scan + FM chain ============
__global__ __launch_bounds__(NTHR, 4) void k_one(
    const float* __restrict__ f0, const float* __restrict__ mod_index,
    const float* __restrict__ freq_ratio, const float* __restrict__ adsr,
    int* __restrict__ flags, int* __restrict__ counter,
    double* __restrict__ vals, float* __restrict__ out) {
  __shared__ __align__(16) float tile[NTHR * EPT];  // 16 KB output staging
  __shared__ double wsum[NTHR / 64];
  __shared__ double cbsh;
  __shared__ int stk;

  int t = threadIdx.x, lane = t & 63, wid = t >> 6;

  // ticket: guarantees every spinning block's predecessors already started
  if (t == 0) stk = atomicAdd(counter, 1);
  __syncthreads();
  int tk = stk;
  int ch = tk >> 5;   // 0..63  (chunk index within row)
  int row = tk & 31;  // 0..31
  size_t rowOff = (size_t)row * T;

  // ---- phase A: load own 16 elements to registers, per-thread f32 sum ----
  const float4* fp4 = (const float4*)(f0 + rowOff + ch * CHUNK + t * EPT);
  float4 v[4];
  float fsum = 0.0f;
#pragma unroll
  for (int q = 0; q < 4; ++q) {
    v[q] = fp4[q];
    fsum += (v[q].x + v[q].y) + (v[q].z + v[q].w);
  }
  double ts = (double)fsum;

  // wave inclusive f64 scan over thread sums
  double x = ts;
#pragma unroll
  for (int d = 1; d < 64; d <<= 1) {
    double n = __shfl_up(x, d);
    if (lane >= d) x += n;
  }
  if (lane == 63) wsum[wid] = x;
  __syncthreads();
  double wbase = 0.0, tot = 0.0;
#pragma unroll
  for (int w = 0; w < NTHR / 64; ++w) {
    double s = wsum[w];
    wbase += (w < wid) ? s : 0.0;
    tot += s;
  }
  // publish chunk aggregate ASAP (value relaxed, flag release)
  if (t == 0) {
    __hip_atomic_store(&vals[tk], tot, __ATOMIC_RELAXED,
                       __HIP_MEMORY_SCOPE_AGENT);
    __hip_atomic_store(&flags[tk], 1, __ATOMIC_RELEASE,
                       __HIP_MEMORY_SCOPE_AGENT);
  }

  // ---- per-op setup (overlaps predecessors' publishing) ----
  const float step = 249.0f / (float)(T - 1);
  int i0 = ch * CHUNK + t * EPT;
  int i0s = (int)floorf((float)i0 * step);
  float pr0 = (float)i0 * step - (float)i0s;  // local frame coord; seg0 pr<1

  float frs[6], c0[6], s0[6], dd6[6];
#pragma unroll
  for (int k = 0; k < 6; ++k) {
    frs[k] = freq_ratio[row * 6 + k] * (1.0f / 16000.0f);
    float em = 2.0f / (1.0f + expf(-mod_index[row * 6 + k]));
    env_params(adsr, row, k, i0s, em, c0[k], s0[k], dd6[k]);
  }

  // ---- lookback: wave 0, lane c spin-waits on predecessor chunk c ----
  if (wid == 0) {
    double pv = 0.0;
    if (lane < ch) {
      int idx = (lane << 5) + row;  // ticket of (row, chunk=lane)
      while (__hip_atomic_load(&flags[idx], __ATOMIC_ACQUIRE,
                               __HIP_MEMORY_SCOPE_AGENT) == 0)
        __builtin_amdgcn_s_sleep(2);
      pv = __hip_atomic_load(&vals[idx], __ATOMIC_RELAXED,
                             __HIP_MEMORY_SCOPE_AGENT);
    }
#pragma unroll
    for (int d = 32; d > 0; d >>= 1) pv += __shfl_down(pv, d);
    if (lane == 0) cbsh = pv;
  }
  __syncthreads();

  float s = (float)(cbsh + wbase + (x - ts));  // exclusive raw-f0 prefix

  // ---- phase B: FM chain from registers; stage results via LDS ----
  float pr = pr0;
#pragma unroll
  for (int q = 0; q < 4; ++q) {
    float res[4];
#pragma unroll
    for (int j = 0; j < 4; ++j) {
      float f0v = (j == 0) ? v[q].x : (j == 1) ? v[q].y
                : (j == 2) ? v[q].z : v[q].w;
      s += f0v;                          // inclusive raw prefix
      float m = fmaxf(pr - 1.0f, 0.0f);  // shared envelope hinge

      auto opk = [&](int k, float mod) {
        float ph = fmaf(frs[k], s, mod);  // phase in revolutions
        float sv = __builtin_amdgcn_sinf(__builtin_amdgcn_fractf(ph));
        float e = fmaf(m, dd6[k], fmaf(pr, s0[k], c0[k]));
        return sv * e;
      };

      float o6 = opk(5, 0.0f);
      float o2 = opk(1, 0.0f);
      float o5 = opk(4, o6);
      float o1 = opk(0, o2);
      float o4 = opk(3, o5);
      float o3 = opk(2, o4);
      res[j] = (o3 + o1) * 0.5f;
      pr += step;
    }
    float4 ov;
    ov.x = res[0]; ov.y = res[1]; ov.z = res[2]; ov.w = res[3];
    *(float4*)&tile[swz16(t, 4 * q)] = ov;  // own slots only
  }
  __syncthreads();

  // coalesced LDS -> global store
  float4* ob = (float4*)(out + rowOff + ch * CHUNK);
#pragma unroll
  for (int i = 0; i < 4; ++i) {
    int li = i * 1024 + t * 4;
    int tt = li >> 4, ee = li & 15;
    ob[i * NTHR + t] = *(const float4*)&tile[swz16(tt, ee)];
  }
}

extern "C" void kernel_launch(void* const* d_in, const int* in_sizes, int n_in,
                              void* d_out, int out_size, void* d_ws, size_t ws_size,
                              hipStream_t stream) {
  const float* mod_index  = (const float*)d_in[0]; // [32,6]
  const float* freq_ratio = (const float*)d_in[1]; // [32,6]
  const float* f0         = (const float*)d_in[2]; // [32,T]
  const float* adsr       = (const float*)d_in[3]; // [32,11]
  float* out = (float*)d_out;

  char* ws = (char*)d_ws;
  int* flags = (int*)ws;                      // 2048 * 4 B
  int* counter = (int*)(ws + NBLK * 4);       // 4 B
  double* vals = (double*)(ws + WS_VALS_OFF); // 2048 * 8 B

  // reset flags + ticket counter every launch (in-stream, graph-capturable)
  hipMemsetAsync(ws, 0, WS_VALS_OFF, stream);
  hipLaunchKernelGGL(k_one, dim3(NBLK), dim3(NTHR), 0, stream,
                     f0, mod_index, freq_ratio, adsr, flags, counter, vals, out);
}

// Round 8
// 113.253 us; speedup vs baseline: 1.0127x; 1.0127x over previous
//
#include <hip/hip_runtime.h>
#include <math.h>

#define B 32
#define T 262144
#define NFR 250
#define NCH 64              // chunks per row
#define CHUNK 4096          // elements per chunk
#define NTHR 256
#define EPT 16              // elements per thread
#define NBLK (B * NCH)      // 2048 blocks

// d_ws layout (bytes):
//   [0, 524288)        flags, one int per ticket, padded to 256 B stride
//   [524288, 524292)   ticket counter
//   [524544, 540928)   vals, double[2048]
// memset clears [0, 524544) every launch.
#define FPAD 64                      // ints per flag slot (256 B)
#define WS_CLEAR (NBLK * 256 + 256)  // flags + counter line
#define WS_VALS_OFF WS_CLEAR

// [256][16] f32 tile swizzle: XOR on e bits [3:2] keeps float4 alignment and
// makes per-owner b128 and linear coalesced b128 both bank-conflict-free.
__device__ __forceinline__ int swz16(int t, int e) {
  return t * 16 + (e ^ ((t & 3) << 2));
}

// Per-op envelope line params at local frame i0s: env*mi = c0 + s0*pr + dd*max(pr-1,0)
__device__ __forceinline__ void env_params(const float* __restrict__ adsr,
                                           int row, int k, int i0s, float em,
                                           float& c0, float& s0, float& dd) {
  const float* ap = adsr + row * 11 + k;
  float fl = ap[0], pk = ap[1];
  float a = fmaxf(ap[2], 1e-5f);
  float de = fmaxf(ap[3], 1e-5f);
  float ss = ap[4];
  float r = fmaxf(ap[5], 1e-5f);
  float ra = 1.0f / a, rd = 1.0f / de, rr = 1.0f / r;
  float e3[3];
#pragma unroll
  for (int j = 0; j < 3; ++j) {
    int fi = i0s + j;
    fi = (fi < NFR - 1) ? fi : NFR - 1;
    float tt = (float)fi * (1.0f / 249.0f);
    float att = fminf(fmaxf(tt * ra, 0.0f), 1.0f);
    float dec = fminf(fmaxf((tt - a) * rd, 0.0f), 1.0f);
    float rel = fminf(fmaxf((tt - (1.0f - r)) * rr, 0.0f), 1.0f);
    float env = att * (1.0f - (1.0f - ss) * dec) * (1.0f - rel);
    e3[j] = fl + (pk - fl) * env;
  }
  c0 = e3[0] * em;
  s0 = (e3[1] - e3[0]) * em;
  dd = (e3[2] - e3[1]) * em - s0;
}

// ============ single-pass ticketed chained-scan + FM chain ============
__global__ __launch_bounds__(NTHR, 4) void k_one(
    const float* __restrict__ f0, const float* __restrict__ mod_index,
    const float* __restrict__ freq_ratio, const float* __restrict__ adsr,
    int* __restrict__ flags, int* __restrict__ counter,
    double* __restrict__ vals, float* __restrict__ out) {
  __shared__ __align__(16) float tile[NTHR * EPT];  // 16 KB output staging
  __shared__ double wsum[NTHR / 64];
  __shared__ double cbsh;
  __shared__ int stk;

  int t = threadIdx.x, lane = t & 63, wid = t >> 6;

  // ticket: any spinning block's predecessors are guaranteed started
  if (t == 0) stk = atomicAdd(counter, 1);
  __syncthreads();
  int tk = stk;
  int ch = tk >> 5;   // 0..63  (chunk index within row) — low chunks first
  int row = tk & 31;  // 0..31
  size_t rowOff = (size_t)row * T;

  // ---- phase A: load own 16 elements to registers, per-thread f32 sum ----
  const float4* fp4 = (const float4*)(f0 + rowOff + ch * CHUNK + t * EPT);
  float4 v[4];
  float fsum = 0.0f;
#pragma unroll
  for (int q = 0; q < 4; ++q) {
    v[q] = fp4[q];
    fsum += (v[q].x + v[q].y) + (v[q].z + v[q].w);
  }
  double ts = (double)fsum;

  // wave inclusive f64 scan over thread sums
  double x = ts;
#pragma unroll
  for (int d = 1; d < 64; d <<= 1) {
    double n = __shfl_up(x, d);
    if (lane >= d) x += n;
  }
  if (lane == 63) wsum[wid] = x;
  __syncthreads();
  double wbase = 0.0, tot = 0.0;
#pragma unroll
  for (int w = 0; w < NTHR / 64; ++w) {
    double s = wsum[w];
    wbase += (w < wid) ? s : 0.0;
    tot += s;
  }
  // publish chunk aggregate ASAP (value relaxed, flag release)
  if (t == 0) {
    __hip_atomic_store(&vals[tk], tot, __ATOMIC_RELAXED,
                       __HIP_MEMORY_SCOPE_AGENT);
    __hip_atomic_store(&flags[tk * FPAD], 1, __ATOMIC_RELEASE,
                       __HIP_MEMORY_SCOPE_AGENT);
  }

  // ---- per-op setup (overlaps predecessors' publishing) ----
  const float step = 249.0f / (float)(T - 1);
  int i0 = ch * CHUNK + t * EPT;
  int i0s = (int)floorf((float)i0 * step);
  float pr0 = (float)i0 * step - (float)i0s;  // local frame coord; seg0 pr<1

  float frs[6], c0[6], s0[6], dd6[6];
#pragma unroll
  for (int k = 0; k < 6; ++k) {
    frs[k] = freq_ratio[row * 6 + k] * (1.0f / 16000.0f);
    float em = 2.0f / (1.0f + expf(-mod_index[row * 6 + k]));
    env_params(adsr, row, k, i0s, em, c0[k], s0[k], dd6[k]);
  }

  // ---- lookback: wave 0, lane c waits on predecessor chunk c (backoff) ----
  if (wid == 0) {
    double pv = 0.0;
    if (lane < ch) {
      int idx = (lane << 5) + row;  // ticket of (row, chunk=lane), idx < tk
      while (__hip_atomic_load(&flags[idx * FPAD], __ATOMIC_ACQUIRE,
                               __HIP_MEMORY_SCOPE_AGENT) == 0)
        __builtin_amdgcn_s_sleep(8);  // ~512 cy backoff; lanes exit as seen
      pv = __hip_atomic_load(&vals[idx], __ATOMIC_RELAXED,
                             __HIP_MEMORY_SCOPE_AGENT);
    }
#pragma unroll
    for (int d = 32; d > 0; d >>= 1) pv += __shfl_down(pv, d);
    if (lane == 0) cbsh = pv;
  }
  __syncthreads();

  float s = (float)(cbsh + wbase + (x - ts));  // exclusive raw-f0 prefix

  // ---- phase B: FM chain from registers; stage results via LDS ----
  float pr = pr0;
#pragma unroll
  for (int q = 0; q < 4; ++q) {
    float res[4];
#pragma unroll
    for (int j = 0; j < 4; ++j) {
      float f0v = (j == 0) ? v[q].x : (j == 1) ? v[q].y
                : (j == 2) ? v[q].z : v[q].w;
      s += f0v;                          // inclusive raw prefix
      float m = fmaxf(pr - 1.0f, 0.0f);  // shared envelope hinge

      auto opk = [&](int k, float mod) {
        float ph = fmaf(frs[k], s, mod);  // phase in revolutions
        float sv = __builtin_amdgcn_sinf(__builtin_amdgcn_fractf(ph));
        float e = fmaf(m, dd6[k], fmaf(pr, s0[k], c0[k]));
        return sv * e;
      };

      float o6 = opk(5, 0.0f);
      float o2 = opk(1, 0.0f);
      float o5 = opk(4, o6);
      float o1 = opk(0, o2);
      float o4 = opk(3, o5);
      float o3 = opk(2, o4);
      res[j] = (o3 + o1) * 0.5f;
      pr += step;
    }
    float4 ov;
    ov.x = res[0]; ov.y = res[1]; ov.z = res[2]; ov.w = res[3];
    *(float4*)&tile[swz16(t, 4 * q)] = ov;  // own slots only
  }
  __syncthreads();

  // coalesced LDS -> global store
  float4* ob = (float4*)(out + rowOff + ch * CHUNK);
#pragma unroll
  for (int i = 0; i < 4; ++i) {
    int li = i * 1024 + t * 4;
    int tt = li >> 4, ee = li & 15;
    ob[i * NTHR + t] = *(const float4*)&tile[swz16(tt, ee)];
  }
}

extern "C" void kernel_launch(void* const* d_in, const int* in_sizes, int n_in,
                              void* d_out, int out_size, void* d_ws, size_t ws_size,
                              hipStream_t stream) {
  const float* mod_index  = (const float*)d_in[0]; // [32,6]
  const float* freq_ratio = (const float*)d_in[1]; // [32,6]
  const float* f0         = (const float*)d_in[2]; // [32,T]
  const float* adsr       = (const float*)d_in[3]; // [32,11]
  float* out = (float*)d_out;

  char* ws = (char*)d_ws;
  int* flags = (int*)ws;                        // 2048 slots * 256 B
  int* counter = (int*)(ws + NBLK * 256);       // own 256 B line
  double* vals = (double*)(ws + WS_VALS_OFF);   // 2048 * 8 B

  // reset flags + ticket counter every launch (in-stream, graph-capturable)
  hipMemsetAsync(ws, 0, WS_CLEAR, stream);
  hipLaunchKernelGGL(k_one, dim3(NBLK), dim3(NTHR), 0, stream,
                     f0, mod_index, freq_ratio, adsr, flags, counter, vals, out);
}

// Round 9
// 107.118 us; speedup vs baseline: 1.0707x; 1.0573x over previous
//
#include <hip/hip_runtime.h>
#include <math.h>

#define B 32
#define T 262144
#define NFR 250
#define NCH 64              // chunks per row
#define CHUNK 4096          // elements per chunk
#define NTHR 256
#define EPT 16              // elements per thread
#define NBLK (B * NCH)      // 2048 blocks

// d_ws layout (bytes):
//   [0, 524288)        flags, one int per ticket, padded to 256 B stride
//   [524288, 524292)   ticket counter (own 256 B line)
//   [524544, 540928)   vals, double[2048]
// memset clears [0, 524544) every launch.
#define FPAD 64                      // ints per flag slot (256 B)
#define WS_CLEAR (NBLK * 256 + 256)  // flags + counter line
#define WS_VALS_OFF WS_CLEAR

// [256][16] f32 tile swizzle: XOR on e bits [3:2] keeps float4 alignment and
// makes per-owner b128 and linear coalesced b128 both bank-conflict-free.
__device__ __forceinline__ int swz16(int t, int e) {
  return t * 16 + (e ^ ((t & 3) << 2));
}

// Per-op envelope line params at local frame i0s: env*mi = c0 + s0*pr + dd*max(pr-1,0)
__device__ __forceinline__ void env_params(const float* __restrict__ adsr,
                                           int row, int k, int i0s, float em,
                                           float& c0, float& s0, float& dd) {
  const float* ap = adsr + row * 11 + k;
  float fl = ap[0], pk = ap[1];
  float a = fmaxf(ap[2], 1e-5f);
  float de = fmaxf(ap[3], 1e-5f);
  float ss = ap[4];
  float r = fmaxf(ap[5], 1e-5f);
  float ra = 1.0f / a, rd = 1.0f / de, rr = 1.0f / r;
  float e3[3];
#pragma unroll
  for (int j = 0; j < 3; ++j) {
    int fi = i0s + j;
    fi = (fi < NFR - 1) ? fi : NFR - 1;
    float tt = (float)fi * (1.0f / 249.0f);
    float att = fminf(fmaxf(tt * ra, 0.0f), 1.0f);
    float dec = fminf(fmaxf((tt - a) * rd, 0.0f), 1.0f);
    float rel = fminf(fmaxf((tt - (1.0f - r)) * rr, 0.0f), 1.0f);
    float env = att * (1.0f - (1.0f - ss) * dec) * (1.0f - rel);
    e3[j] = fl + (pk - fl) * env;
  }
  c0 = e3[0] * em;
  s0 = (e3[1] - e3[0]) * em;
  dd = (e3[2] - e3[1]) * em - s0;
}

// ============ single-pass ticketed chained-scan + FM chain ============
__global__ __launch_bounds__(NTHR, 4) void k_one(
    const float* __restrict__ f0, const float* __restrict__ mod_index,
    const float* __restrict__ freq_ratio, const float* __restrict__ adsr,
    int* __restrict__ flags, int* __restrict__ counter,
    double* __restrict__ vals, float* __restrict__ out) {
  __shared__ __align__(16) float tile[NTHR * EPT];  // 16 KB output staging
  __shared__ double wsum[NTHR / 64];
  __shared__ double cbsh;
  __shared__ int stk;

  int t = threadIdx.x, lane = t & 63, wid = t >> 6;

  // ticket: any spinning block's predecessors are guaranteed started
  if (t == 0) stk = atomicAdd(counter, 1);
  __syncthreads();
  int tk = stk;
  int ch = tk >> 5;   // 0..63  (chunk index within row) — low chunks first
  int row = tk & 31;  // 0..31
  size_t rowOff = (size_t)row * T;

  // ---- phase A: load own 16 elements to registers, per-thread f32 sum ----
  const float4* fp4 = (const float4*)(f0 + rowOff + ch * CHUNK + t * EPT);
  float4 v[4];
  float fsum = 0.0f;
#pragma unroll
  for (int q = 0; q < 4; ++q) {
    v[q] = fp4[q];
    fsum += (v[q].x + v[q].y) + (v[q].z + v[q].w);
  }
  double ts = (double)fsum;

  // wave inclusive f64 scan over thread sums
  double x = ts;
#pragma unroll
  for (int d = 1; d < 64; d <<= 1) {
    double n = __shfl_up(x, d);
    if (lane >= d) x += n;
  }
  if (lane == 63) wsum[wid] = x;
  __syncthreads();
  double wbase = 0.0, tot = 0.0;
#pragma unroll
  for (int w = 0; w < NTHR / 64; ++w) {
    double s = wsum[w];
    wbase += (w < wid) ? s : 0.0;
    tot += s;
  }
  // publish chunk aggregate ASAP (value relaxed, flag release — once/block)
  if (t == 0) {
    __hip_atomic_store(&vals[tk], tot, __ATOMIC_RELAXED,
                       __HIP_MEMORY_SCOPE_AGENT);
    __hip_atomic_store(&flags[tk * FPAD], 1, __ATOMIC_RELEASE,
                       __HIP_MEMORY_SCOPE_AGENT);
  }

  // ---- per-op setup (overlaps predecessors' publishing) ----
  const float step = 249.0f / (float)(T - 1);
  int i0 = ch * CHUNK + t * EPT;
  int i0s = (int)floorf((float)i0 * step);
  float pr0 = (float)i0 * step - (float)i0s;  // local frame coord; seg0 pr<1

  float frs[6], c0[6], s0[6], dd6[6];
#pragma unroll
  for (int k = 0; k < 6; ++k) {
    frs[k] = freq_ratio[row * 6 + k] * (1.0f / 16000.0f);
    float em = 2.0f / (1.0f + expf(-mod_index[row * 6 + k]));
    env_params(adsr, row, k, i0s, em, c0[k], s0[k], dd6[k]);
  }

  // ---- lookback: RELAXED polls (no per-poll cache invalidate), then ONE
  //      acquire fence per wave before reading vals. ----
  if (wid == 0) {
    int idx = (lane << 5) + row;  // ticket of (row, chunk=lane), idx < tk
    bool active = lane < ch;
    if (active) {
      while (__hip_atomic_load(&flags[idx * FPAD], __ATOMIC_RELAXED,
                               __HIP_MEMORY_SCOPE_AGENT) == 0)
        __builtin_amdgcn_s_sleep(4);  // ~256 cy backoff; lanes exit as seen
    }
    __builtin_amdgcn_fence(__ATOMIC_ACQUIRE, "agent");  // once per wave
    double pv = 0.0;
    if (active)
      pv = __hip_atomic_load(&vals[idx], __ATOMIC_RELAXED,
                             __HIP_MEMORY_SCOPE_AGENT);
#pragma unroll
    for (int d = 32; d > 0; d >>= 1) pv += __shfl_down(pv, d);
    if (lane == 0) cbsh = pv;
  }
  __syncthreads();

  float s = (float)(cbsh + wbase + (x - ts));  // exclusive raw-f0 prefix

  // ---- phase B: FM chain from registers; stage results via LDS ----
  float pr = pr0;
#pragma unroll
  for (int q = 0; q < 4; ++q) {
    float res[4];
#pragma unroll
    for (int j = 0; j < 4; ++j) {
      float f0v = (j == 0) ? v[q].x : (j == 1) ? v[q].y
                : (j == 2) ? v[q].z : v[q].w;
      s += f0v;                          // inclusive raw prefix
      float m = fmaxf(pr - 1.0f, 0.0f);  // shared envelope hinge

      auto opk = [&](int k, float mod) {
        float ph = fmaf(frs[k], s, mod);  // phase in revolutions
        float sv = __builtin_amdgcn_sinf(__builtin_amdgcn_fractf(ph));
        float e = fmaf(m, dd6[k], fmaf(pr, s0[k], c0[k]));
        return sv * e;
      };

      float o6 = opk(5, 0.0f);
      float o2 = opk(1, 0.0f);
      float o5 = opk(4, o6);
      float o1 = opk(0, o2);
      float o4 = opk(3, o5);
      float o3 = opk(2, o4);
      res[j] = (o3 + o1) * 0.5f;
      pr += step;
    }
    float4 ov;
    ov.x = res[0]; ov.y = res[1]; ov.z = res[2]; ov.w = res[3];
    *(float4*)&tile[swz16(t, 4 * q)] = ov;  // own slots only
  }
  __syncthreads();

  // coalesced LDS -> global store
  float4* ob = (float4*)(out + rowOff + ch * CHUNK);
#pragma unroll
  for (int i = 0; i < 4; ++i) {
    int li = i * 1024 + t * 4;
    int tt = li >> 4, ee = li & 15;
    ob[i * NTHR + t] = *(const float4*)&tile[swz16(tt, ee)];
  }
}

extern "C" void kernel_launch(void* const* d_in, const int* in_sizes, int n_in,
                              void* d_out, int out_size, void* d_ws, size_t ws_size,
                              hipStream_t stream) {
  const float* mod_index  = (const float*)d_in[0]; // [32,6]
  const float* freq_ratio = (const float*)d_in[1]; // [32,6]
  const float* f0         = (const float*)d_in[2]; // [32,T]
  const float* adsr       = (const float*)d_in[3]; // [32,11]
  float* out = (float*)d_out;

  char* ws = (char*)d_ws;
  int* flags = (int*)ws;                        // 2048 slots * 256 B
  int* counter = (int*)(ws + NBLK * 256);       // own 256 B line
  double* vals = (double*)(ws + WS_VALS_OFF);   // 2048 * 8 B

  // reset flags + ticket counter every launch (in-stream, graph-capturable)
  hipMemsetAsync(ws, 0, WS_CLEAR, stream);
  hipLaunchKernelGGL(k_one, dim3(NBLK), dim3(NTHR), 0, stream,
                     f0, mod_index, freq_ratio, adsr, flags, counter, vals, out);
}

// Round 10
// 32.929 us; speedup vs baseline: 3.4829x; 3.2530x over previous
//
#include <hip/hip_runtime.h>
#include <math.h>

#define B 32
#define T 262144
#define NFR 250
#define NCH 64              // chunks per row
#define CHUNK 4096          // elements per chunk
#define NTHR 256
#define EPT 16              // elements per thread (contiguous ownership)

#define STEPF (249.0f / 262143.0f)  // frame step per sample

// [256][16] f32 tile swizzle: XOR on e bits [3:2] keeps float4 alignment and
// makes per-owner b128 and linear coalesced b128 both bank-conflict-free.
__device__ __forceinline__ int swz16(int t, int e) {
  return t * 16 + (e ^ ((t & 3) << 2));
}

// Per-op envelope line params at local frame i0s: env*em = c0 + s0*pr + dd*max(pr-1,0)
__device__ __forceinline__ void env_params(const float* __restrict__ adsr,
                                           int row, int k, int i0s, float em,
                                           float& c0, float& s0, float& dd) {
  const float* ap = adsr + row * 11 + k;
  float fl = ap[0], pk = ap[1];
  float a = fmaxf(ap[2], 1e-5f);
  float de = fmaxf(ap[3], 1e-5f);
  float ss = ap[4];
  float r = fmaxf(ap[5], 1e-5f);
  float ra = 1.0f / a, rd = 1.0f / de, rr = 1.0f / r;
  float e3[3];
#pragma unroll
  for (int j = 0; j < 3; ++j) {
    int fi = i0s + j;
    fi = (fi < NFR - 1) ? fi : NFR - 1;
    float tt = (float)fi * (1.0f / 249.0f);
    float att = fminf(fmaxf(tt * ra, 0.0f), 1.0f);
    float dec = fminf(fmaxf((tt - a) * rd, 0.0f), 1.0f);
    float rel = fminf(fmaxf((tt - (1.0f - r)) * rr, 0.0f), 1.0f);
    float env = att * (1.0f - (1.0f - ss) * dec) * (1.0f - rel);
    e3[j] = fl + (pk - fl) * env;
  }
  c0 = e3[0] * em;
  s0 = (e3[1] - e3[0]) * em;
  dd = (e3[2] - e3[1]) * em - s0;
}

// ---------------- kernel 1: per-chunk f64 sums of f0 (coalesced) ----------------
__global__ __launch_bounds__(NTHR) void k_partial(const float* __restrict__ f0,
                                                  double* __restrict__ partials) {
  int row = blockIdx.y, ch = blockIdx.x, t = threadIdx.x;
  const float4* p = (const float4*)(f0 + (size_t)row * T + ch * CHUNK);
  double s = 0.0;
#pragma unroll
  for (int i = 0; i < CHUNK / 4 / NTHR; ++i) {  // 4 coalesced float4 loads
    float4 v = p[i * NTHR + t];
    s += (double)v.x + (double)v.y + (double)v.z + (double)v.w;
  }
#pragma unroll
  for (int d = 32; d > 0; d >>= 1) s += __shfl_down(s, d);
  __shared__ double wsum[NTHR / 64];
  int lane = t & 63, wid = t >> 6;
  if (lane == 0) wsum[wid] = s;
  __syncthreads();
  if (t == 0) {
    double tot = 0.0;
#pragma unroll
    for (int w = 0; w < NTHR / 64; ++w) tot += wsum[w];
    __hip_atomic_store(&partials[row * NCH + ch], tot, __ATOMIC_RELAXED,
                       __HIP_MEMORY_SCOPE_AGENT);
  }
}

// ------- kernel 2: scan + stage-wise ILP FM chain, LDS-staged store -------
__global__ __launch_bounds__(NTHR, 4) void k_main(const float* __restrict__ f0,
                                                  const float* __restrict__ mod_index,
                                                  const float* __restrict__ freq_ratio,
                                                  const float* __restrict__ adsr,
                                                  const double* __restrict__ partials,
                                                  float* __restrict__ out) {
  __shared__ __align__(16) float tile[NTHR * EPT];  // 16 KB output staging
  __shared__ double wsum[NTHR / 64];

  int row = blockIdx.y, ch = blockIdx.x, t = threadIdx.x;
  int lane = t & 63, wid = t >> 6;
  size_t rowOff = (size_t)row * T;

  // ---- load own 16 elements straight to registers ----
  const float4* fp4 = (const float4*)(f0 + rowOff + ch * CHUNK + t * EPT);
  float4 v4[4];
#pragma unroll
  for (int q = 0; q < 4; ++q) v4[q] = fp4[q];
  float f[EPT];
#pragma unroll
  for (int q = 0; q < 4; ++q) {
    f[4 * q] = v4[q].x; f[4 * q + 1] = v4[q].y;
    f[4 * q + 2] = v4[q].z; f[4 * q + 3] = v4[q].w;
  }
  float fsum = 0.0f;
#pragma unroll
  for (int q = 0; q < 4; ++q)
    fsum += (f[4 * q] + f[4 * q + 1]) + (f[4 * q + 2] + f[4 * q + 3]);
  double ts = (double)fsum;

  // ---- wave inclusive f64 scan over thread sums ----
  double x = ts;
#pragma unroll
  for (int d = 1; d < 64; d <<= 1) {
    double n = __shfl_up(x, d);
    if (lane >= d) x += n;
  }
  if (lane == 63) wsum[wid] = x;

  // ---- chunk base: each wave redundantly reduces preceding chunk sums ----
  double pv = 0.0;
  if (lane < ch)  // NCH=64 fits one 64-lane wave exactly
    pv = __hip_atomic_load(&partials[row * NCH + lane], __ATOMIC_RELAXED,
                           __HIP_MEMORY_SCOPE_AGENT);
#pragma unroll
  for (int d = 32; d > 0; d >>= 1) pv += __shfl_down(pv, d);
  double cbase = __shfl(pv, 0);

  __syncthreads();  // wsum ready
  double wbase = 0.0;
#pragma unroll
  for (int w = 0; w < NTHR / 64; ++w) wbase += (w < wid) ? wsum[w] : 0.0;
  float sbase = (float)(cbase + wbase + (x - ts));  // exclusive raw-f0 prefix

  // ---- per-op constants; 0.5 output scale folded into ops 0 and 2 ----
  int i0 = ch * CHUNK + t * EPT;
  int i0s = (int)floorf((float)i0 * STEPF);
  float pr0 = (float)i0 * STEPF - (float)i0s;  // local frame coord; seg0 pr<1

  float frs[6], c0[6], s0[6], dd6[6];
#pragma unroll
  for (int k = 0; k < 6; ++k) {
    frs[k] = freq_ratio[row * 6 + k] * (1.0f / 16000.0f);
    float em = 2.0f / (1.0f + expf(-mod_index[row * 6 + k]));
    if (k == 0 || k == 2) em *= 0.5f;  // (o3 + o1)/2 folded in
    env_params(adsr, row, k, i0s, em, c0[k], s0[k], dd6[k]);
  }

  // ---- inclusive prefixes for all 16 elements (short serial adds) ----
  float sv[EPT];
  {
    float a = sbase;
#pragma unroll
    for (int e = 0; e < EPT; ++e) { a += f[e]; sv[e] = a; }
  }

  auto envf = [&](int k, int e) -> float {
    float pr = pr0 + (float)e * STEPF;       // e*STEPF is a literal
    float m = fmaxf(pr - 1.0f, 0.0f);        // hinge at frame boundary
    return fmaf(m, dd6[k], fmaf(pr, s0[k], c0[k]));
  };

  // ---- stage-wise FM chain: 16 independent sins in flight per stage ----
  float o[EPT];
#pragma unroll
  for (int e = 0; e < EPT; ++e)   // op6 (no mod)
    o[e] = __builtin_amdgcn_sinf(__builtin_amdgcn_fractf(frs[5] * sv[e])) * envf(5, e);
#pragma unroll
  for (int e = 0; e < EPT; ++e)   // op5
    o[e] = __builtin_amdgcn_sinf(__builtin_amdgcn_fractf(fmaf(frs[4], sv[e], o[e]))) * envf(4, e);
#pragma unroll
  for (int e = 0; e < EPT; ++e)   // op4
    o[e] = __builtin_amdgcn_sinf(__builtin_amdgcn_fractf(fmaf(frs[3], sv[e], o[e]))) * envf(3, e);
#pragma unroll
  for (int e = 0; e < EPT; ++e)   // op3 (env pre-halved)
    o[e] = __builtin_amdgcn_sinf(__builtin_amdgcn_fractf(fmaf(frs[2], sv[e], o[e]))) * envf(2, e);
#pragma unroll
  for (int e = 0; e < EPT; ++e) { // op2 -> op1 (env pre-halved), add to o3
    float p2 = __builtin_amdgcn_sinf(__builtin_amdgcn_fractf(frs[1] * sv[e])) * envf(1, e);
    float p1 = __builtin_amdgcn_sinf(__builtin_amdgcn_fractf(fmaf(frs[0], sv[e], p2))) * envf(0, e);
    o[e] += p1;
  }

  // ---- stage results in own LDS slots; coalesced store ----
#pragma unroll
  for (int q = 0; q < 4; ++q) {
    float4 ov;
    ov.x = o[4 * q]; ov.y = o[4 * q + 1];
    ov.z = o[4 * q + 2]; ov.w = o[4 * q + 3];
    *(float4*)&tile[swz16(t, 4 * q)] = ov;
  }
  __syncthreads();

  float4* ob = (float4*)(out + rowOff + ch * CHUNK);
#pragma unroll
  for (int i = 0; i < 4; ++i) {
    int li = i * 1024 + t * 4;
    int tt = li >> 4, ee = li & 15;
    ob[i * NTHR + t] = *(const float4*)&tile[swz16(tt, ee)];
  }
}

extern "C" void kernel_launch(void* const* d_in, const int* in_sizes, int n_in,
                              void* d_out, int out_size, void* d_ws, size_t ws_size,
                              hipStream_t stream) {
  const float* mod_index  = (const float*)d_in[0]; // [32,6]
  const float* freq_ratio = (const float*)d_in[1]; // [32,6]
  const float* f0         = (const float*)d_in[2]; // [32,T]
  const float* adsr       = (const float*)d_in[3]; // [32,11]
  float* out = (float*)d_out;

  double* partials = (double*)d_ws;  // 32*64*8 = 16384 bytes

  hipLaunchKernelGGL(k_partial, dim3(NCH, B), dim3(NTHR), 0, stream, f0, partials);
  hipLaunchKernelGGL(k_main, dim3(NCH, B), dim3(NTHR), 0, stream,
                     f0, mod_index, freq_ratio, adsr, partials, out);
}

// Round 11
// 31.814 us; speedup vs baseline: 3.6050x; 1.0350x over previous
//
#include <hip/hip_runtime.h>
#include <math.h>

#define B 32
#define T 262144
#define NFR 250
#define NCH 64              // chunks per row
#define CHUNK 4096          // elements per chunk
#define NTHR 256
#define EPT 16              // elements per thread (contiguous ownership)

#define STEPF (249.0f / 262143.0f)  // frame step per sample

// [256][16] f32 tile swizzle: XOR on e bits [3:2] keeps float4 alignment and
// makes per-owner b128 and linear coalesced b128 both bank-conflict-free.
__device__ __forceinline__ int swz16(int t, int e) {
  return t * 16 + (e ^ ((t & 3) << 2));
}

// Per-op envelope line params at local frame i0s: env*em = c0 + s0*pr + dd*max(pr-1,0)
__device__ __forceinline__ void env_params(const float* __restrict__ adsr,
                                           int row, int k, int i0s, float em,
                                           float& c0, float& s0, float& dd) {
  const float* ap = adsr + row * 11 + k;
  float fl = ap[0], pk = ap[1];
  float a = fmaxf(ap[2], 1e-5f);
  float de = fmaxf(ap[3], 1e-5f);
  float ss = ap[4];
  float r = fmaxf(ap[5], 1e-5f);
  float ra = 1.0f / a, rd = 1.0f / de, rr = 1.0f / r;
  float e3[3];
#pragma unroll
  for (int j = 0; j < 3; ++j) {
    int fi = i0s + j;
    fi = (fi < NFR - 1) ? fi : NFR - 1;
    float tt = (float)fi * (1.0f / 249.0f);
    float att = fminf(fmaxf(tt * ra, 0.0f), 1.0f);
    float dec = fminf(fmaxf((tt - a) * rd, 0.0f), 1.0f);
    float rel = fminf(fmaxf((tt - (1.0f - r)) * rr, 0.0f), 1.0f);
    float env = att * (1.0f - (1.0f - ss) * dec) * (1.0f - rel);
    e3[j] = fl + (pk - fl) * env;
  }
  c0 = e3[0] * em;
  s0 = (e3[1] - e3[0]) * em;
  dd = (e3[2] - e3[1]) * em - s0;
}

// ---------------- kernel 1: per-chunk f64 sums of f0 (coalesced) ----------------
__global__ __launch_bounds__(NTHR) void k_partial(const float* __restrict__ f0,
                                                  double* __restrict__ partials) {
  int row = blockIdx.y, ch = blockIdx.x, t = threadIdx.x;
  const float4* p = (const float4*)(f0 + (size_t)row * T + ch * CHUNK);
  double s = 0.0;
#pragma unroll
  for (int i = 0; i < CHUNK / 4 / NTHR; ++i) {  // 4 coalesced float4 loads
    float4 v = p[i * NTHR + t];
    s += (double)v.x + (double)v.y + (double)v.z + (double)v.w;
  }
#pragma unroll
  for (int d = 32; d > 0; d >>= 1) s += __shfl_down(s, d);
  __shared__ double wsum[NTHR / 64];
  int lane = t & 63, wid = t >> 6;
  if (lane == 0) wsum[wid] = s;
  __syncthreads();
  if (t == 0) {
    double tot = 0.0;
#pragma unroll
    for (int w = 0; w < NTHR / 64; ++w) tot += wsum[w];
    __hip_atomic_store(&partials[row * NCH + ch], tot, __ATOMIC_RELAXED,
                       __HIP_MEMORY_SCOPE_AGENT);
  }
}

// ------- kernel 2: scan + half-wise ILP FM chain, LDS-staged store -------
__global__ __launch_bounds__(NTHR, 6) void k_main(const float* __restrict__ f0,
                                                  const float* __restrict__ mod_index,
                                                  const float* __restrict__ freq_ratio,
                                                  const float* __restrict__ adsr,
                                                  const double* __restrict__ partials,
                                                  float* __restrict__ out) {
  __shared__ __align__(16) float tile[NTHR * EPT];  // 16 KB output staging
  __shared__ double wsum[NTHR / 64];

  int row = blockIdx.y, ch = blockIdx.x, t = threadIdx.x;
  int lane = t & 63, wid = t >> 6;
  size_t rowOff = (size_t)row * T;

  // ---- issue own 16-element loads first (latency hidden by setup below) ----
  const float4* fp4 = (const float4*)(f0 + rowOff + ch * CHUNK + t * EPT);
  float4 v4[4];
#pragma unroll
  for (int q = 0; q < 4; ++q) v4[q] = fp4[q];

  // ---- chunk base: wave-parallel reduce of preceding chunk sums ----
  double pv = 0.0;
  if (lane < ch)  // NCH=64 fits one 64-lane wave exactly
    pv = __hip_atomic_load(&partials[row * NCH + lane], __ATOMIC_RELAXED,
                           __HIP_MEMORY_SCOPE_AGENT);
#pragma unroll
  for (int d = 32; d > 0; d >>= 1) pv += __shfl_down(pv, d);
  double cbase = __shfl(pv, 0);

  // ---- per-op constants (VALU work overlapping the f0 load latency) ----
  int i0 = ch * CHUNK + t * EPT;
  int i0s = (int)floorf((float)i0 * STEPF);
  float pr0 = (float)i0 * STEPF - (float)i0s;  // local frame coord; seg0 pr<1

  float frs[6], c0[6], s0[6], dd6[6];
#pragma unroll
  for (int k = 0; k < 6; ++k) {
    frs[k] = freq_ratio[row * 6 + k] * (1.0f / 16000.0f);
    float em = 2.0f / (1.0f + expf(-mod_index[row * 6 + k]));
    if (k == 0 || k == 2) em *= 0.5f;  // (o3 + o1)/2 folded in
    env_params(adsr, row, k, i0s, em, c0[k], s0[k], dd6[k]);
  }

  // ---- consume loads: relative inclusive prefix (f discarded) ----
  float sv[EPT];
  {
    float a = 0.0f;
#pragma unroll
    for (int q = 0; q < 4; ++q) {
      a += v4[q].x; sv[4 * q] = a;
      a += v4[q].y; sv[4 * q + 1] = a;
      a += v4[q].z; sv[4 * q + 2] = a;
      a += v4[q].w; sv[4 * q + 3] = a;
    }
  }
  double ts = (double)sv[EPT - 1];

  // ---- wave inclusive f64 scan over thread sums ----
  double x = ts;
#pragma unroll
  for (int d = 1; d < 64; d <<= 1) {
    double n = __shfl_up(x, d);
    if (lane >= d) x += n;
  }
  if (lane == 63) wsum[wid] = x;
  __syncthreads();  // wsum ready
  double wbase = 0.0;
#pragma unroll
  for (int w = 0; w < NTHR / 64; ++w) wbase += (w < wid) ? wsum[w] : 0.0;
  float sbase = (float)(cbase + wbase + (x - ts));  // exclusive raw-f0 prefix

  // absolute inclusive prefixes
#pragma unroll
  for (int e = 0; e < EPT; ++e) sv[e] += sbase;

  auto envf = [&](int k, int e) -> float {  // pr/m CSE'd across stages
    float pr = pr0 + (float)e * STEPF;
    float m = fmaxf(pr - 1.0f, 0.0f);
    return fmaf(m, dd6[k], fmaf(pr, s0[k], c0[k]));
  };

  // ---- half-wise stage-parallel FM chain (8 indep sins per stage) ----
#pragma unroll
  for (int h = 0; h < 2; ++h) {
    const int b0 = h * 8;
    float o[8];
#pragma unroll
    for (int e = 0; e < 8; ++e)   // op6 (no mod)
      o[e] = __builtin_amdgcn_sinf(__builtin_amdgcn_fractf(frs[5] * sv[b0 + e])) * envf(5, b0 + e);
#pragma unroll
    for (int e = 0; e < 8; ++e)   // op5
      o[e] = __builtin_amdgcn_sinf(__builtin_amdgcn_fractf(fmaf(frs[4], sv[b0 + e], o[e]))) * envf(4, b0 + e);
#pragma unroll
    for (int e = 0; e < 8; ++e)   // op4
      o[e] = __builtin_amdgcn_sinf(__builtin_amdgcn_fractf(fmaf(frs[3], sv[b0 + e], o[e]))) * envf(3, b0 + e);
#pragma unroll
    for (int e = 0; e < 8; ++e)   // op3 (env pre-halved)
      o[e] = __builtin_amdgcn_sinf(__builtin_amdgcn_fractf(fmaf(frs[2], sv[b0 + e], o[e]))) * envf(2, b0 + e);
#pragma unroll
    for (int e = 0; e < 8; ++e) { // op2 -> op1 (env pre-halved), add to o3
      float p2 = __builtin_amdgcn_sinf(__builtin_amdgcn_fractf(frs[1] * sv[b0 + e])) * envf(1, b0 + e);
      float p1 = __builtin_amdgcn_sinf(__builtin_amdgcn_fractf(fmaf(frs[0], sv[b0 + e], p2))) * envf(0, b0 + e);
      o[e] += p1;
    }
#pragma unroll
    for (int q = 0; q < 2; ++q) { // stage this half into own LDS slots
      float4 ov;
      ov.x = o[4 * q]; ov.y = o[4 * q + 1];
      ov.z = o[4 * q + 2]; ov.w = o[4 * q + 3];
      *(float4*)&tile[swz16(t, b0 + 4 * q)] = ov;
    }
  }
  __syncthreads();

  // ---- coalesced LDS -> global store ----
  float4* ob = (float4*)(out + rowOff + ch * CHUNK);
#pragma unroll
  for (int i = 0; i < 4; ++i) {
    int li = i * 1024 + t * 4;
    int tt = li >> 4, ee = li & 15;
    ob[i * NTHR + t] = *(const float4*)&tile[swz16(tt, ee)];
  }
}

extern "C" void kernel_launch(void* const* d_in, const int* in_sizes, int n_in,
                              void* d_out, int out_size, void* d_ws, size_t ws_size,
                              hipStream_t stream) {
  const float* mod_index  = (const float*)d_in[0]; // [32,6]
  const float* freq_ratio = (const float*)d_in[1]; // [32,6]
  const float* f0         = (const float*)d_in[2]; // [32,T]
  const float* adsr       = (const float*)d_in[3]; // [32,11]
  float* out = (float*)d_out;

  double* partials = (double*)d_ws;  // 32*64*8 = 16384 bytes

  hipLaunchKernelGGL(k_partial, dim3(NCH, B), dim3(NTHR), 0, stream, f0, partials);
  hipLaunchKernelGGL(k_main, dim3(NCH, B), dim3(NTHR), 0, stream,
                     f0, mod_index, freq_ratio, adsr, partials, out);
}